// Round 16
// baseline (72.078 us; speedup 1.0000x reference)
//
#include <hip/hip_runtime.h>

#define HID 64

typedef _Float16 half2v __attribute__((ext_vector_type(2)));
typedef _Float16 half8  __attribute__((ext_vector_type(8)));
typedef float    f32x4  __attribute__((ext_vector_type(4)));

__device__ inline unsigned packh2(float a, float b) {
    half2v v; v.x = (_Float16)a; v.y = (_Float16)b;
    return __builtin_bit_cast(unsigned, v);
}
__device__ inline float tanh_fast(float x) {
    return 1.0f - __fdividef(2.0f, __expf(2.0f * x) + 1.0f);
}
__device__ inline uint4 pack8f(const float* __restrict__ p) {
    return make_uint4(packh2(p[0], p[1]), packh2(p[2], p[3]),
                      packh2(p[4], p[5]), packh2(p[6], p[7]));
}
__device__ inline f32x4 mfma16(uint4 a, uint4 b, f32x4 c) {
    return __builtin_amdgcn_mfma_f32_16x16x32_f16(
        __builtin_bit_cast(half8, a), __builtin_bit_cast(half8, b), c, 0, 0, 0);
}

// Per-wave LDS scratch. x: stride 72 f16 (2-way-free banks, 16B-aligned rows).
struct __align__(16) WaveLDS {
    _Float16 x[16 * 72];   // x1, then reused for x2
    float lr2[16 * 68];    // low-rank-2 per-h contribution
    float g07[16 * 8];     // g rows 0..7 (a1)
    float b3v[16 * 4];     // g rows 1032..1035 (b3)
};

// ONE kernel: per wave = 16 samples. Hypernet g computed EXACTLY per sample
// via MFMA over Wh2 (streamed sequentially; no precomputed table, no gathers,
// no knot quantization). lane: grp=l>>4 (k/row-quad group), sl=l&15 (sample
// = MFMA column = A-row index for frag loads).
__global__ __launch_bounds__(256) void hyper_fused(
    const float* __restrict__ coords, const float* __restrict__ param,
    const float* __restrict__ W1, const float* __restrict__ B1,
    const float* __restrict__ W2, const float* __restrict__ B2,
    const float* __restrict__ W3, const float* __restrict__ B3,
    const float* __restrict__ Wh1, const float* __restrict__ Bh1,
    const float* __restrict__ Wh2, const float* __restrict__ Bh2,
    float* __restrict__ out, int n) {
    __shared__ WaveLDS S[4];
    const int tid = threadIdx.x;
    const int wid = tid >> 6;
    const int l = tid & 63;
    const int grp = l >> 4;
    const int sl = l & 15;
    WaveLDS& W = S[wid];

    const int s0 = blockIdx.x * 64 + wid * 16;
    int s = s0 + sl;
    if (s >= n) s = n - 1;
    const float p = param[s];
    const float2 c = ((const float2*)coords)[s];

    // ---- h = tanh(p*Wh1+Bh1) for this lane's 16 k's: EXACTLY the B-frags ----
    float hv[16];
    {
        const float* w1p = Wh1 + grp * 8;
        const float* b1p = Bh1 + grp * 8;
        #pragma unroll
        for (int i = 0; i < 8; ++i) hv[i]     = tanh_fast(fmaf(p, w1p[i],      b1p[i]));
        #pragma unroll
        for (int i = 0; i < 8; ++i) hv[8 + i] = tanh_fast(fmaf(p, w1p[32 + i], b1p[32 + i]));
    }
    const uint4 hA = make_uint4(packh2(hv[0], hv[1]), packh2(hv[2], hv[3]),
                                packh2(hv[4], hv[5]), packh2(hv[6], hv[7]));
    const uint4 hB = make_uint4(packh2(hv[8], hv[9]), packh2(hv[10], hv[11]),
                                packh2(hv[12], hv[13]), packh2(hv[14], hv[15]));

    // ---- combined tile: rows 0..7 (a1) + rows 1032..1035 (b3) ----
    {
        int row = (sl < 8) ? sl : (1024 + sl);
        if (row > 1035) row = 1035;                 // m=12..15 garbage, ignored
        const float* ar = Wh2 + row * HID + grp * 8;
        f32x4 a = {0.f, 0.f, 0.f, 0.f};
        a = mfma16(pack8f(ar), hA, a);
        a = mfma16(pack8f(ar + 32), hB, a);
        if (grp == 0) {
            const float4 bq = *(const float4*)(Bh2 + 0);
            W.g07[sl * 8 + 0] = a[0] + bq.x; W.g07[sl * 8 + 1] = a[1] + bq.y;
            W.g07[sl * 8 + 2] = a[2] + bq.z; W.g07[sl * 8 + 3] = a[3] + bq.w;
        } else if (grp == 1) {
            const float4 bq = *(const float4*)(Bh2 + 4);
            W.g07[sl * 8 + 4] = a[0] + bq.x; W.g07[sl * 8 + 5] = a[1] + bq.y;
            W.g07[sl * 8 + 6] = a[2] + bq.z; W.g07[sl * 8 + 7] = a[3] + bq.w;
        } else if (grp == 2) {
            const float4 bq = *(const float4*)(Bh2 + 1032);
            W.b3v[sl * 4 + 0] = a[0] + bq.x; W.b3v[sl * 4 + 1] = a[1] + bq.y;
            W.b3v[sl * 4 + 2] = a[2] + bq.z; W.b3v[sl * 4 + 3] = a[3] + bq.w;
        }
    }
    // t1[r] = c . a1[r][:]  (all lanes; cross-lane via LDS, same-wave ordering)
    float t1v[4];
    {
        const float* g0 = W.g07 + sl * 8;
        #pragma unroll
        for (int r = 0; r < 4; ++r) t1v[r] = fmaf(c.x, g0[2 * r], c.y * g0[2 * r + 1]);
    }

    // ---- b1 (rows 8..263): lane's D-quad = b1[h=4t+grp][0..3] -> x1[h] ----
    #pragma unroll
    for (int t = 0; t < 16; ++t) {
        const float* ar = Wh2 + (8 + 16 * t + sl) * HID + grp * 8;
        f32x4 a = {0.f, 0.f, 0.f, 0.f};
        a = mfma16(pack8f(ar), hA, a);
        a = mfma16(pack8f(ar + 32), hB, a);
        const float4 bq = *(const float4*)(Bh2 + 8 + 16 * t + 4 * grp);
        const float lr1 = (a[0] + bq.x) * t1v[0] + (a[1] + bq.y) * t1v[1]
                        + (a[2] + bq.z) * t1v[2] + (a[3] + bq.w) * t1v[3];
        const int h1 = 4 * t + grp;
        const float x1 = tanh_fast(fmaf(c.x, W1[2 * h1],
                                    fmaf(c.y, W1[2 * h1 + 1], B1[h1] + lr1)));
        W.x[sl * 72 + h1] = (_Float16)x1;
    }

    // ---- W2 @ X1 : 8 MFMAs (W2 frags converted inline) ----
    const uint4 xb1 = *(const uint4*)(W.x + sl * 72 + grp * 8);
    const uint4 xb2 = *(const uint4*)(W.x + sl * 72 + 32 + grp * 8);
    f32x4 acc2[4];
    #pragma unroll
    for (int hb = 0; hb < 4; ++hb) {
        const float* wr = W2 + (hb * 16 + sl) * HID + grp * 8;
        f32x4 a = {0.f, 0.f, 0.f, 0.f};
        a = mfma16(pack8f(wr), xb1, a);
        acc2[hb] = mfma16(pack8f(wr + 32), xb2, a);
    }

    // ---- a2 (rows 264..519): t2[r] partials, r = t>>2 static ----
    float t2p[4] = {0.f, 0.f, 0.f, 0.f};
    #pragma unroll
    for (int t = 0; t < 16; ++t) {
        const float* ar = Wh2 + (264 + 16 * t + sl) * HID + grp * 8;
        f32x4 a = {0.f, 0.f, 0.f, 0.f};
        a = mfma16(pack8f(ar), hA, a);
        a = mfma16(pack8f(ar + 32), hB, a);
        const float4 bq = *(const float4*)(Bh2 + 264 + 16 * t + 4 * grp);
        const _Float16* xp = W.x + sl * 72 + ((16 * t) & 63) + 4 * grp;
        t2p[t >> 2] += (a[0] + bq.x) * (float)xp[0] + (a[1] + bq.y) * (float)xp[1]
                     + (a[2] + bq.z) * (float)xp[2] + (a[3] + bq.w) * (float)xp[3];
    }
    float t2v[4];
    #pragma unroll
    for (int r = 0; r < 4; ++r) {
        float v = t2p[r];
        v += __shfl_xor(v, 16);
        v += __shfl_xor(v, 32);
        t2v[r] = v;
    }

    // ---- b2 (rows 520..775): lr2[h=4t+grp] = b2[h][:] . t2 ----
    #pragma unroll
    for (int t = 0; t < 16; ++t) {
        const float* ar = Wh2 + (520 + 16 * t + sl) * HID + grp * 8;
        f32x4 a = {0.f, 0.f, 0.f, 0.f};
        a = mfma16(pack8f(ar), hA, a);
        a = mfma16(pack8f(ar + 32), hB, a);
        const float4 bq = *(const float4*)(Bh2 + 520 + 16 * t + 4 * grp);
        W.lr2[sl * 68 + 4 * t + grp] =
              (a[0] + bq.x) * t2v[0] + (a[1] + bq.y) * t2v[1]
            + (a[2] + bq.z) * t2v[2] + (a[3] + bq.w) * t2v[3];
    }

    // ---- x2 at D-lanes (h = hb*16+4grp+reg); op += W3.x2; x2 -> LDS ----
    float op = 0.f;
    #pragma unroll
    for (int hb = 0; hb < 4; ++hb) {
        const int hh = hb * 16 + 4 * grp;
        const float4 lrq = *(const float4*)(W.lr2 + sl * 68 + hh);
        const float4 b2q = *(const float4*)(B2 + hh);
        const float4 w3q = *(const float4*)(W3 + hh);
        const float x20 = tanh_fast(acc2[hb][0] + lrq.x + b2q.x);
        const float x21 = tanh_fast(acc2[hb][1] + lrq.y + b2q.y);
        const float x22 = tanh_fast(acc2[hb][2] + lrq.z + b2q.z);
        const float x23 = tanh_fast(acc2[hb][3] + lrq.w + b2q.w);
        op = fmaf(w3q.x, x20, fmaf(w3q.y, x21, fmaf(w3q.z, x22, fmaf(w3q.w, x23, op))));
        *(uint2*)(W.x + sl * 72 + hh) = make_uint2(packh2(x20, x21), packh2(x22, x23));
    }

    // ---- a3 (rows 776..1031): t3[r] partials against x2 ----
    float t3p[4] = {0.f, 0.f, 0.f, 0.f};
    #pragma unroll
    for (int t = 0; t < 16; ++t) {
        const float* ar = Wh2 + (776 + 16 * t + sl) * HID + grp * 8;
        f32x4 a = {0.f, 0.f, 0.f, 0.f};
        a = mfma16(pack8f(ar), hA, a);
        a = mfma16(pack8f(ar + 32), hB, a);
        const float4 bq = *(const float4*)(Bh2 + 776 + 16 * t + 4 * grp);
        const _Float16* xp = W.x + sl * 72 + ((16 * t) & 63) + 4 * grp;
        t3p[t >> 2] += (a[0] + bq.x) * (float)xp[0] + (a[1] + bq.y) * (float)xp[1]
                     + (a[2] + bq.z) * (float)xp[2] + (a[3] + bq.w) * (float)xp[3];
    }
    float t3v[4];
    #pragma unroll
    for (int r = 0; r < 4; ++r) {
        float v = t3p[r];
        v += __shfl_xor(v, 16);
        v += __shfl_xor(v, 32);
        t3v[r] = v;
    }

    // ---- output ----
    op += __shfl_xor(op, 16);
    op += __shfl_xor(op, 32);
    if (grp == 0 && (s0 + sl) < n) {
        const float* b3p = W.b3v + sl * 4;
        out[s0 + sl] = op + b3p[0] * t3v[0] + b3p[1] * t3v[1]
                          + b3p[2] * t3v[2] + b3p[3] * t3v[3] + B3[0];
    }
}

extern "C" void kernel_launch(void* const* d_in, const int* in_sizes, int n_in,
                              void* d_out, int out_size, void* d_ws, size_t ws_size,
                              hipStream_t stream) {
    const float* coords = (const float*)d_in[0];
    const float* param  = (const float*)d_in[1];
    const float* W1  = (const float*)d_in[2];
    const float* B1  = (const float*)d_in[3];
    const float* W2  = (const float*)d_in[4];
    const float* B2  = (const float*)d_in[5];
    const float* W3  = (const float*)d_in[6];
    const float* B3  = (const float*)d_in[7];
    const float* Wh1 = (const float*)d_in[8];
    const float* Bh1 = (const float*)d_in[9];
    const float* Wh2 = (const float*)d_in[10];
    const float* Bh2 = (const float*)d_in[11];
    float* out = (float*)d_out;
    const int n = out_size;                 // 32768 samples

    const int nblocks = (n + 63) / 64;      // 64 samples/block (4 waves x 16)
    hyper_fused<<<nblocks, 256, 0, stream>>>(coords, param, W1, B1, W2, B2,
                                             W3, B3, Wh1, Bh1, Wh2, Bh2, out, n);
}

// Round 17
// 52.945 us; speedup vs baseline: 1.3614x; 1.3614x over previous
//
#include <hip/hip_runtime.h>

#define HID 64

typedef _Float16 half2v __attribute__((ext_vector_type(2)));
typedef _Float16 half8  __attribute__((ext_vector_type(8)));
typedef float    f32x4  __attribute__((ext_vector_type(4)));

// Precomputed f16 MFMA A-fragments:
//  tile 0      : combined a1(rows0..7)/b3(rows1032..1035) tile
//  tiles 1..16 : b1 (rows 8..263)     tiles 17..32: a2 (264..519)
//  tiles 33..48: b2 (520..775)        tiles 49..64: a3 (776..1031)
//  tiles 65..68: W2 (4 x 16-row tiles)
// FR[t*128 + q*64 + l] : q = K-half (0: k0..31, 1: k32..63), l = lane.
#define NTILE 69
__device__ __align__(16) uint4 FR[NTILE * 128];   // 141 KB

__device__ inline unsigned packh2(float a, float b) {
    half2v v; v.x = (_Float16)a; v.y = (_Float16)b;
    return __builtin_bit_cast(unsigned, v);
}
__device__ inline float tanh_fast(float x) {
    return 1.0f - __fdividef(2.0f, __expf(2.0f * x) + 1.0f);
}
__device__ inline uint4 pack8f(const float* __restrict__ p) {
    return make_uint4(packh2(p[0], p[1]), packh2(p[2], p[3]),
                      packh2(p[4], p[5]), packh2(p[6], p[7]));
}
__device__ inline f32x4 mfma16(uint4 a, uint4 b, f32x4 c) {
    return __builtin_amdgcn_mfma_f32_16x16x32_f16(
        __builtin_bit_cast(half8, a), __builtin_bit_cast(half8, b), c, 0, 0, 0);
}

// Prep: 69 blocks x 128 threads; thread packs one uint4 (8 f32 -> 8 f16).
__global__ __launch_bounds__(128) void prep_frags(
    const float* __restrict__ Wh2, const float* __restrict__ W2) {
    const int t = blockIdx.x;
    const int i = threadIdx.x;
    const int q = i >> 6;          // K-half
    const int l = i & 63;
    const int m = l & 15;          // A-row within tile (= MFMA output row idx)
    const int kg = l >> 4;         // col group
    const float* src;
    if (t == 0) {
        int row = (m < 8) ? m : (1024 + m);
        if (row > 1035) row = 1035;
        src = Wh2 + row * HID + q * 32 + kg * 8;
    } else if (t <= 64) {
        const int sec = (t - 1) >> 4;          // 0:b1 1:a2 2:b2 3:a3
        const int tt = (t - 1) & 15;
        src = Wh2 + (8 + sec * 256 + 16 * tt + m) * HID + q * 32 + kg * 8;
    } else {
        const int hb = t - 65;
        src = W2 + (hb * 16 + m) * HID + q * 32 + kg * 8;
    }
    FR[t * 128 + q * 64 + l] = pack8f(src);
}

// Per-wave LDS scratch. x: stride 72 f16 (2-way-free banks, 16B-aligned rows).
struct __align__(16) WaveLDS {
    _Float16 x[16 * 72];   // x1, then reused for x2
    float lr2[16 * 68];    // low-rank-2 per-h contribution
    float g07[16 * 8];     // g rows 0..7 (a1)
    float b3v[16 * 4];     // g rows 1032..1035 (b3)
};

// Main: per wave = 16 samples; hypernet g computed exactly via MFMA with
// PRECOMPUTED coalesced A-frags. lane: grp=l>>4, sl=l&15 (sample/B-column).
__global__ __launch_bounds__(256) void hyper_fused(
    const float* __restrict__ coords, const float* __restrict__ param,
    const float* __restrict__ W1, const float* __restrict__ B1,
    const float* __restrict__ B2, const float* __restrict__ W3,
    const float* __restrict__ B3,
    const float* __restrict__ Wh1, const float* __restrict__ Bh1,
    const float* __restrict__ Bh2,
    float* __restrict__ out, int n) {
    __shared__ WaveLDS S[4];
    const int tid = threadIdx.x;
    const int wid = tid >> 6;
    const int l = tid & 63;
    const int grp = l >> 4;
    const int sl = l & 15;
    WaveLDS& W = S[wid];

    const int s0 = blockIdx.x * 64 + wid * 16;
    int s = s0 + sl;
    if (s >= n) s = n - 1;
    const float p = param[s];
    const float2 c = ((const float2*)coords)[s];

    // ---- h = tanh(p*Wh1+Bh1): exactly this lane's B-fragment k-slots ----
    float hv[16];
    {
        const float* w1p = Wh1 + grp * 8;
        const float* b1p = Bh1 + grp * 8;
        #pragma unroll
        for (int i = 0; i < 8; ++i) hv[i]     = tanh_fast(fmaf(p, w1p[i],      b1p[i]));
        #pragma unroll
        for (int i = 0; i < 8; ++i) hv[8 + i] = tanh_fast(fmaf(p, w1p[32 + i], b1p[32 + i]));
    }
    const uint4 hA = make_uint4(packh2(hv[0], hv[1]), packh2(hv[2], hv[3]),
                                packh2(hv[4], hv[5]), packh2(hv[6], hv[7]));
    const uint4 hB = make_uint4(packh2(hv[8], hv[9]), packh2(hv[10], hv[11]),
                                packh2(hv[12], hv[13]), packh2(hv[14], hv[15]));

    // ---- combined tile 0: rows 0..7 (a1) + 1032..1035 (b3) ----
    {
        f32x4 a = {0.f, 0.f, 0.f, 0.f};
        a = mfma16(FR[l], hA, a);
        a = mfma16(FR[64 + l], hB, a);
        if (grp == 0) {
            const float4 bq = *(const float4*)(Bh2 + 0);
            W.g07[sl * 8 + 0] = a[0] + bq.x; W.g07[sl * 8 + 1] = a[1] + bq.y;
            W.g07[sl * 8 + 2] = a[2] + bq.z; W.g07[sl * 8 + 3] = a[3] + bq.w;
        } else if (grp == 1) {
            const float4 bq = *(const float4*)(Bh2 + 4);
            W.g07[sl * 8 + 4] = a[0] + bq.x; W.g07[sl * 8 + 5] = a[1] + bq.y;
            W.g07[sl * 8 + 6] = a[2] + bq.z; W.g07[sl * 8 + 7] = a[3] + bq.w;
        } else if (grp == 2) {
            const float4 bq = *(const float4*)(Bh2 + 1032);
            W.b3v[sl * 4 + 0] = a[0] + bq.x; W.b3v[sl * 4 + 1] = a[1] + bq.y;
            W.b3v[sl * 4 + 2] = a[2] + bq.z; W.b3v[sl * 4 + 3] = a[3] + bq.w;
        }
    }
    float t1v[4];
    {
        const float* g0 = W.g07 + sl * 8;
        #pragma unroll
        for (int r = 0; r < 4; ++r) t1v[r] = fmaf(c.x, g0[2 * r], c.y * g0[2 * r + 1]);
    }

    // ---- b1 (tiles 1..16): D-quad = b1[h=4t+grp][0..3] -> x1[h] ----
    #pragma unroll
    for (int t = 0; t < 16; ++t) {
        const uint4* fr = FR + (1 + t) * 128;
        f32x4 a = {0.f, 0.f, 0.f, 0.f};
        a = mfma16(fr[l], hA, a);
        a = mfma16(fr[64 + l], hB, a);
        const float4 bq = *(const float4*)(Bh2 + 8 + 16 * t + 4 * grp);
        const float lr1 = (a[0] + bq.x) * t1v[0] + (a[1] + bq.y) * t1v[1]
                        + (a[2] + bq.z) * t1v[2] + (a[3] + bq.w) * t1v[3];
        const int h1 = 4 * t + grp;
        const float x1 = tanh_fast(fmaf(c.x, W1[2 * h1],
                                    fmaf(c.y, W1[2 * h1 + 1], B1[h1] + lr1)));
        W.x[sl * 72 + h1] = (_Float16)x1;
    }

    // ---- W2 @ X1 (tiles 65..68) ----
    const uint4 xb1 = *(const uint4*)(W.x + sl * 72 + grp * 8);
    const uint4 xb2 = *(const uint4*)(W.x + sl * 72 + 32 + grp * 8);
    f32x4 acc2[4];
    #pragma unroll
    for (int hb = 0; hb < 4; ++hb) {
        const uint4* fr = FR + (65 + hb) * 128;
        f32x4 a = {0.f, 0.f, 0.f, 0.f};
        a = mfma16(fr[l], xb1, a);
        acc2[hb] = mfma16(fr[64 + l], xb2, a);
    }

    // ---- a2 (tiles 17..32): t2[r] partials (r = t>>2, static) ----
    float t2p[4] = {0.f, 0.f, 0.f, 0.f};
    #pragma unroll
    for (int t = 0; t < 16; ++t) {
        const uint4* fr = FR + (17 + t) * 128;
        f32x4 a = {0.f, 0.f, 0.f, 0.f};
        a = mfma16(fr[l], hA, a);
        a = mfma16(fr[64 + l], hB, a);
        const float4 bq = *(const float4*)(Bh2 + 264 + 16 * t + 4 * grp);
        const _Float16* xp = W.x + sl * 72 + ((16 * t) & 63) + 4 * grp;
        t2p[t >> 2] += (a[0] + bq.x) * (float)xp[0] + (a[1] + bq.y) * (float)xp[1]
                     + (a[2] + bq.z) * (float)xp[2] + (a[3] + bq.w) * (float)xp[3];
    }
    float t2v[4];
    #pragma unroll
    for (int r = 0; r < 4; ++r) {
        float v = t2p[r];
        v += __shfl_xor(v, 16);
        v += __shfl_xor(v, 32);
        t2v[r] = v;
    }

    // ---- b2 (tiles 33..48): lr2[h=4t+grp] = b2[h][:] . t2 ----
    #pragma unroll
    for (int t = 0; t < 16; ++t) {
        const uint4* fr = FR + (33 + t) * 128;
        f32x4 a = {0.f, 0.f, 0.f, 0.f};
        a = mfma16(fr[l], hA, a);
        a = mfma16(fr[64 + l], hB, a);
        const float4 bq = *(const float4*)(Bh2 + 520 + 16 * t + 4 * grp);
        W.lr2[sl * 68 + 4 * t + grp] =
              (a[0] + bq.x) * t2v[0] + (a[1] + bq.y) * t2v[1]
            + (a[2] + bq.z) * t2v[2] + (a[3] + bq.w) * t2v[3];
    }

    // ---- x2 at D-lanes; op += W3.x2; x2 -> LDS ----
    float op = 0.f;
    #pragma unroll
    for (int hb = 0; hb < 4; ++hb) {
        const int hh = hb * 16 + 4 * grp;
        const float4 lrq = *(const float4*)(W.lr2 + sl * 68 + hh);
        const float4 b2q = *(const float4*)(B2 + hh);
        const float4 w3q = *(const float4*)(W3 + hh);
        const float x20 = tanh_fast(acc2[hb][0] + lrq.x + b2q.x);
        const float x21 = tanh_fast(acc2[hb][1] + lrq.y + b2q.y);
        const float x22 = tanh_fast(acc2[hb][2] + lrq.z + b2q.z);
        const float x23 = tanh_fast(acc2[hb][3] + lrq.w + b2q.w);
        op = fmaf(w3q.x, x20, fmaf(w3q.y, x21, fmaf(w3q.z, x22, fmaf(w3q.w, x23, op))));
        *(uint2*)(W.x + sl * 72 + hh) = make_uint2(packh2(x20, x21), packh2(x22, x23));
    }

    // ---- a3 (tiles 49..64): t3[r] partials against x2 ----
    float t3p[4] = {0.f, 0.f, 0.f, 0.f};
    #pragma unroll
    for (int t = 0; t < 16; ++t) {
        const uint4* fr = FR + (49 + t) * 128;
        f32x4 a = {0.f, 0.f, 0.f, 0.f};
        a = mfma16(fr[l], hA, a);
        a = mfma16(fr[64 + l], hB, a);
        const float4 bq = *(const float4*)(Bh2 + 776 + 16 * t + 4 * grp);
        const _Float16* xp = W.x + sl * 72 + ((16 * t) & 63) + 4 * grp;
        t3p[t >> 2] += (a[0] + bq.x) * (float)xp[0] + (a[1] + bq.y) * (float)xp[1]
                     + (a[2] + bq.z) * (float)xp[2] + (a[3] + bq.w) * (float)xp[3];
    }
    float t3v[4];
    #pragma unroll
    for (int r = 0; r < 4; ++r) {
        float v = t3p[r];
        v += __shfl_xor(v, 16);
        v += __shfl_xor(v, 32);
        t3v[r] = v;
    }

    // ---- output ----
    op += __shfl_xor(op, 16);
    op += __shfl_xor(op, 32);
    if (grp == 0 && (s0 + sl) < n) {
        const float* b3p = W.b3v + sl * 4;
        out[s0 + sl] = op + b3p[0] * t3v[0] + b3p[1] * t3v[1]
                          + b3p[2] * t3v[2] + b3p[3] * t3v[3] + B3[0];
    }
}

extern "C" void kernel_launch(void* const* d_in, const int* in_sizes, int n_in,
                              void* d_out, int out_size, void* d_ws, size_t ws_size,
                              hipStream_t stream) {
    const float* coords = (const float*)d_in[0];
    const float* param  = (const float*)d_in[1];
    const float* W1  = (const float*)d_in[2];
    const float* B1  = (const float*)d_in[3];
    const float* W2  = (const float*)d_in[4];
    const float* B2  = (const float*)d_in[5];
    const float* W3  = (const float*)d_in[6];
    const float* B3  = (const float*)d_in[7];
    const float* Wh1 = (const float*)d_in[8];
    const float* Bh1 = (const float*)d_in[9];
    const float* Wh2 = (const float*)d_in[10];
    const float* Bh2 = (const float*)d_in[11];
    float* out = (float*)d_out;
    const int n = out_size;                 // 32768 samples

    prep_frags<<<NTILE, 128, 0, stream>>>(Wh2, W2);

    const int nblocks = (n + 63) / 64;      // 64 samples/block (4 waves x 16)
    hyper_fused<<<nblocks, 256, 0, stream>>>(coords, param, W1, B1, B2,
                                             W3, B3, Wh1, Bh1, Bh2, out, n);
}

// Round 18
// 29.351 us; speedup vs baseline: 2.4557x; 1.8038x over previous
//
#include <hip/hip_runtime.h>

#define HID 64

typedef _Float16 half2v __attribute__((ext_vector_type(2)));
typedef _Float16 half8  __attribute__((ext_vector_type(8)));
typedef float    f32x4  __attribute__((ext_vector_type(4)));

// Precomputed f16 MFMA A-fragments (verified R17):
//  tile 0      : combined a1(rows0..7)/b3(rows1032..1035) tile
//  tiles 1..16 : b1 (rows 8..263)     tiles 17..32: a2 (264..519)
//  tiles 33..48: b2 (520..775)        tiles 49..64: a3 (776..1031)
//  tiles 65..68: W2 (4 x 16-row tiles)
#define NTILE 69
__device__ __align__(16) uint4 FR[NTILE * 128];   // 141 KB

__device__ inline unsigned packh2(float a, float b) {
    half2v v; v.x = (_Float16)a; v.y = (_Float16)b;
    return __builtin_bit_cast(unsigned, v);
}
__device__ inline float tanh_fast(float x) {
    return 1.0f - __fdividef(2.0f, __expf(2.0f * x) + 1.0f);
}
__device__ inline uint4 pack8f(const float* __restrict__ p) {
    return make_uint4(packh2(p[0], p[1]), packh2(p[2], p[3]),
                      packh2(p[4], p[5]), packh2(p[6], p[7]));
}
__device__ inline f32x4 mfma16(uint4 a, uint4 b, f32x4 c) {
    return __builtin_amdgcn_mfma_f32_16x16x32_f16(
        __builtin_bit_cast(half8, a), __builtin_bit_cast(half8, b), c, 0, 0, 0);
}

__global__ __launch_bounds__(128) void prep_frags(
    const float* __restrict__ Wh2, const float* __restrict__ W2) {
    const int t = blockIdx.x;
    const int i = threadIdx.x;
    const int q = i >> 6;
    const int l = i & 63;
    const int m = l & 15;
    const int kg = l >> 4;
    const float* src;
    if (t == 0) {
        int row = (m < 8) ? m : (1024 + m);
        if (row > 1035) row = 1035;
        src = Wh2 + row * HID + q * 32 + kg * 8;
    } else if (t <= 64) {
        const int sec = (t - 1) >> 4;
        const int tt = (t - 1) & 15;
        src = Wh2 + (8 + sec * 256 + 16 * tt + m) * HID + q * 32 + kg * 8;
    } else {
        const int hb = t - 65;
        src = W2 + (hb * 16 + m) * HID + q * 32 + kg * 8;
    }
    FR[t * 128 + q * 64 + l] = pack8f(src);
}

// Main: ONE BLOCK (4 waves) per 16 samples; the 65 work-tiles are SPLIT
// across the 4 waves (4 tiles/wave/phase) with LDS hand-off. Grid = 2048
// blocks -> 8 blocks/CU -> 32 waves/CU (vs R17's 8): TLP hides the
// load->mfma chains. lane: grp=l>>4, sl=l&15 (sample).
__global__ __launch_bounds__(256) void hyper_fused(
    const float* __restrict__ coords, const float* __restrict__ param,
    const float* __restrict__ W1, const float* __restrict__ B1,
    const float* __restrict__ B2, const float* __restrict__ W3,
    const float* __restrict__ B3,
    const float* __restrict__ Wh1, const float* __restrict__ Bh1,
    const float* __restrict__ Bh2,
    float* __restrict__ out, int n) {
    __shared__ __align__(16) _Float16 xs[16 * 72];   // x1 then x2
    __shared__ __align__(16) float lr2s[16 * 68];
    __shared__ float g07[4][16 * 8];
    __shared__ float b3vs[4][16 * 4];
    __shared__ float t2s[4][16], t3s[4][16], opp[4][16];

    const int tid = threadIdx.x;
    const int wid = tid >> 6;
    const int l = tid & 63;
    const int grp = l >> 4;
    const int sl = l & 15;

    const int s0 = blockIdx.x * 16;
    int s = s0 + sl;
    if (s >= n) s = n - 1;
    const float p = param[s];
    const float2 c = ((const float2*)coords)[s];

    // ---- h = tanh(p*Wh1+Bh1): this lane's B-fragment k-slots (all waves) ----
    float hv[16];
    {
        const float* w1p = Wh1 + grp * 8;
        const float* b1p = Bh1 + grp * 8;
        #pragma unroll
        for (int i = 0; i < 8; ++i) hv[i]     = tanh_fast(fmaf(p, w1p[i],      b1p[i]));
        #pragma unroll
        for (int i = 0; i < 8; ++i) hv[8 + i] = tanh_fast(fmaf(p, w1p[32 + i], b1p[32 + i]));
    }
    const uint4 hA = make_uint4(packh2(hv[0], hv[1]), packh2(hv[2], hv[3]),
                                packh2(hv[4], hv[5]), packh2(hv[6], hv[7]));
    const uint4 hB = make_uint4(packh2(hv[8], hv[9]), packh2(hv[10], hv[11]),
                                packh2(hv[12], hv[13]), packh2(hv[14], hv[15]));

    // ---- tile 0 (a1/b3), redundant per wave; per-wave scratch, no barrier ----
    {
        f32x4 a = {0.f, 0.f, 0.f, 0.f};
        a = mfma16(FR[l], hA, a);
        a = mfma16(FR[64 + l], hB, a);
        if (grp == 0) {
            const float4 bq = *(const float4*)(Bh2 + 0);
            g07[wid][sl * 8 + 0] = a[0] + bq.x; g07[wid][sl * 8 + 1] = a[1] + bq.y;
            g07[wid][sl * 8 + 2] = a[2] + bq.z; g07[wid][sl * 8 + 3] = a[3] + bq.w;
        } else if (grp == 1) {
            const float4 bq = *(const float4*)(Bh2 + 4);
            g07[wid][sl * 8 + 4] = a[0] + bq.x; g07[wid][sl * 8 + 5] = a[1] + bq.y;
            g07[wid][sl * 8 + 6] = a[2] + bq.z; g07[wid][sl * 8 + 7] = a[3] + bq.w;
        } else if (grp == 2) {
            const float4 bq = *(const float4*)(Bh2 + 1032);
            b3vs[wid][sl * 4 + 0] = a[0] + bq.x; b3vs[wid][sl * 4 + 1] = a[1] + bq.y;
            b3vs[wid][sl * 4 + 2] = a[2] + bq.z; b3vs[wid][sl * 4 + 3] = a[3] + bq.w;
        }
    }
    float t1v[4];
    {
        const float* g0 = g07[wid] + sl * 8;
        #pragma unroll
        for (int r = 0; r < 4; ++r) t1v[r] = fmaf(c.x, g0[2 * r], c.y * g0[2 * r + 1]);
    }

    // ---- phase B: b1 tiles, wave w does local tiles 4w..4w+3 -> x1 ----
    #pragma unroll
    for (int i = 0; i < 4; ++i) {
        const int lt = 4 * wid + i;
        const uint4* fr = FR + (1 + lt) * 128;
        f32x4 a = {0.f, 0.f, 0.f, 0.f};
        a = mfma16(fr[l], hA, a);
        a = mfma16(fr[64 + l], hB, a);
        const float4 bq = *(const float4*)(Bh2 + 8 + 16 * lt + 4 * grp);
        const float lr1 = (a[0] + bq.x) * t1v[0] + (a[1] + bq.y) * t1v[1]
                        + (a[2] + bq.z) * t1v[2] + (a[3] + bq.w) * t1v[3];
        const int h1 = 4 * lt + grp;
        const float x1 = tanh_fast(fmaf(c.x, W1[2 * h1],
                                    fmaf(c.y, W1[2 * h1 + 1], B1[h1] + lr1)));
        xs[sl * 72 + h1] = (_Float16)x1;
    }
    __syncthreads();

    // ---- phase C: W2 tile (65+wid) -> acc2 for hb = wid ----
    const uint4 xb1 = *(const uint4*)(xs + sl * 72 + grp * 8);
    const uint4 xb2 = *(const uint4*)(xs + sl * 72 + 32 + grp * 8);
    f32x4 acc2;
    {
        const uint4* fr = FR + (65 + wid) * 128;
        f32x4 a = {0.f, 0.f, 0.f, 0.f};
        a = mfma16(fr[l], xb1, a);
        acc2 = mfma16(fr[64 + l], xb2, a);
    }

    // ---- phase D: a2 tiles 4w..4w+3 (all rank r = wid) -> t2s[wid] ----
    {
        float t2p = 0.f;
        #pragma unroll
        for (int i = 0; i < 4; ++i) {
            const int lt = 4 * wid + i;
            const uint4* fr = FR + (17 + lt) * 128;
            f32x4 a = {0.f, 0.f, 0.f, 0.f};
            a = mfma16(fr[l], hA, a);
            a = mfma16(fr[64 + l], hB, a);
            const float4 bq = *(const float4*)(Bh2 + 264 + 16 * lt + 4 * grp);
            const _Float16* xp = xs + sl * 72 + ((16 * lt) & 63) + 4 * grp;
            t2p += (a[0] + bq.x) * (float)xp[0] + (a[1] + bq.y) * (float)xp[1]
                 + (a[2] + bq.z) * (float)xp[2] + (a[3] + bq.w) * (float)xp[3];
        }
        t2p += __shfl_xor(t2p, 16);
        t2p += __shfl_xor(t2p, 32);
        if (l < 16) t2s[wid][l] = t2p;
    }
    __syncthreads();

    // ---- phase E: b2 tiles 4w..4w+3 -> lr2s for h in [16w,16w+16) ----
    {
        const float t20 = t2s[0][sl], t21 = t2s[1][sl],
                    t22 = t2s[2][sl], t23 = t2s[3][sl];
        #pragma unroll
        for (int i = 0; i < 4; ++i) {
            const int lt = 4 * wid + i;
            const uint4* fr = FR + (33 + lt) * 128;
            f32x4 a = {0.f, 0.f, 0.f, 0.f};
            a = mfma16(fr[l], hA, a);
            a = mfma16(fr[64 + l], hB, a);
            const float4 bq = *(const float4*)(Bh2 + 520 + 16 * lt + 4 * grp);
            lr2s[sl * 68 + 4 * lt + grp] =
                  (a[0] + bq.x) * t20 + (a[1] + bq.y) * t21
                + (a[2] + bq.z) * t22 + (a[3] + bq.w) * t23;
        }
    }
    __syncthreads();

    // ---- phase F: x2 for hb=wid quad; op partial; x2 -> xs ----
    {
        const int hh = wid * 16 + 4 * grp;
        const float4 lrq = *(const float4*)(lr2s + sl * 68 + hh);
        const float4 b2q = *(const float4*)(B2 + hh);
        const float4 w3q = *(const float4*)(W3 + hh);
        const float x20 = tanh_fast(acc2[0] + lrq.x + b2q.x);
        const float x21 = tanh_fast(acc2[1] + lrq.y + b2q.y);
        const float x22 = tanh_fast(acc2[2] + lrq.z + b2q.z);
        const float x23 = tanh_fast(acc2[3] + lrq.w + b2q.w);
        float op = fmaf(w3q.x, x20, fmaf(w3q.y, x21,
                   fmaf(w3q.z, x22, w3q.w * x23)));
        *(uint2*)(xs + sl * 72 + hh) = make_uint2(packh2(x20, x21), packh2(x22, x23));
        op += __shfl_xor(op, 16);
        op += __shfl_xor(op, 32);
        if (l < 16) opp[wid][l] = op;
    }
    __syncthreads();

    // ---- phase G: a3 tiles 4w..4w+3 (rank r = wid) vs x2 -> t3s[wid] ----
    {
        float t3p = 0.f;
        #pragma unroll
        for (int i = 0; i < 4; ++i) {
            const int lt = 4 * wid + i;
            const uint4* fr = FR + (49 + lt) * 128;
            f32x4 a = {0.f, 0.f, 0.f, 0.f};
            a = mfma16(fr[l], hA, a);
            a = mfma16(fr[64 + l], hB, a);
            const float4 bq = *(const float4*)(Bh2 + 776 + 16 * lt + 4 * grp);
            const _Float16* xp = xs + sl * 72 + ((16 * lt) & 63) + 4 * grp;
            t3p += (a[0] + bq.x) * (float)xp[0] + (a[1] + bq.y) * (float)xp[1]
                 + (a[2] + bq.z) * (float)xp[2] + (a[3] + bq.w) * (float)xp[3];
        }
        t3p += __shfl_xor(t3p, 16);
        t3p += __shfl_xor(t3p, 32);
        if (l < 16) t3s[wid][l] = t3p;
    }
    __syncthreads();

    // ---- phase H: wave 0 combines and stores ----
    if (wid == 0 && l < 16 && (s0 + l) < n) {
        const float o = opp[0][l] + opp[1][l] + opp[2][l] + opp[3][l];
        const float* b3p = b3vs[0] + l * 4;
        out[s0 + l] = o + b3p[0] * t3s[0][l] + b3p[1] * t3s[1][l]
                        + b3p[2] * t3s[2][l] + b3p[3] * t3s[3][l] + B3[0];
    }
}

extern "C" void kernel_launch(void* const* d_in, const int* in_sizes, int n_in,
                              void* d_out, int out_size, void* d_ws, size_t ws_size,
                              hipStream_t stream) {
    const float* coords = (const float*)d_in[0];
    const float* param  = (const float*)d_in[1];
    const float* W1  = (const float*)d_in[2];
    const float* B1  = (const float*)d_in[3];
    const float* W2  = (const float*)d_in[4];
    const float* B2  = (const float*)d_in[5];
    const float* W3  = (const float*)d_in[6];
    const float* B3  = (const float*)d_in[7];
    const float* Wh1 = (const float*)d_in[8];
    const float* Bh1 = (const float*)d_in[9];
    const float* Wh2 = (const float*)d_in[10];
    const float* Bh2 = (const float*)d_in[11];
    float* out = (float*)d_out;
    const int n = out_size;                 // 32768 samples

    prep_frags<<<NTILE, 128, 0, stream>>>(Wh2, W2);

    const int nblocks = (n + 15) / 16;      // 16 samples/block, 4 waves share
    hyper_fused<<<nblocks, 256, 0, stream>>>(coords, param, W1, B1, B2,
                                             W3, B3, Wh1, Bh1, Bh2, out, n);
}